// Round 11
// baseline (280.414 us; speedup 1.0000x reference)
//
#include <hip/hip_runtime.h>
#include <hip/hip_bf16.h>

// Problem: B=2048 pairs, D=512, K=32 features.
// out[b] = relu(x1[b]^T W[:,:,k] x2[b] + V[k].concat(x1,x2) + b[k]) @ U
// GEMM: T = x1_bf16 [2048x512] @ Wt_bf16^T, fused e-contraction with f32 x2.
// R7: 175us, gemm 51us, BANK_CONFLICT 4.98M. R8 swizzle: conflicts ->786K
//     but gemm dur UNCHANGED (stall hidden under barrier drain; T2-gate).
// R10: 155.6us = prep + gemm(50.7) + reduce + gaps -> ~105us in sub-50.3
//     hogs invisible to top-5.
// R11: (a) gemm jg=4 grouping: block loops 4 j-tiles, e-contraction accums
//     in persistent LDS h_accum[128][32]; hpart 32MB -> 8MB ([b][32jg][32k]).
//     (b) reduce_out: wave-per-b, shfl_xor j-reduce, no LDS, no serial stage.
// Workspace: x1b (2MB) | Wt (16.8MB) | hpart (8MB) | vout (256KB).

#define BATCH 2048
#define DIM 512
#define KF 32
#define NCOL (DIM * KF)      // 16384
#define JT (NCOL / 128)      // 128 column tiles
#define JG 32                // j-groups (4 tiles each)

typedef __attribute__((ext_vector_type(8))) short bf16x8;
typedef __attribute__((ext_vector_type(4))) float f32x4;
typedef __attribute__((address_space(1))) const unsigned int gas_u32;
typedef __attribute__((address_space(3))) unsigned int las_u32;

static __device__ __forceinline__ ushort f2bf(float x) {
    __hip_bfloat16 h = __float2bfloat16(x);
    union { __hip_bfloat16 h; ushort u; } cv; cv.h = h;
    return cv.u;
}

// ---- fused prep: vout [0,256) | cvt_x1 [256,1280) | cvt_wt [1280,3328) ----
__global__ void fused_prep_kernel(const float* __restrict__ x1,
                                  const float* __restrict__ x2,
                                  const float* __restrict__ W,
                                  const float* __restrict__ V,
                                  ushort* __restrict__ x1b,
                                  ushort* __restrict__ Wt,
                                  float* __restrict__ vout) {
    __shared__ __align__(16) char sbuf[32768];
    const int bx = blockIdx.x;
    const int t = threadIdx.x;

    if (bx < 256) {
        // ---- vout: vout[b][k] = concat(x1[b],x2[b]) . V[k], k-unrolled x4 ----
        float (*xs)[1024] = (float(*)[1024])sbuf;   // 8 rows x 1024
        const int b0 = bx * 8;
        #pragma unroll
        for (int it = 0; it < 4; ++it) {
            int q = it * 256 + t;
            int r = q >> 7;
            int c = (q & 127) * 4;
            *(float4*)&xs[r][c]       = *(const float4*)&x1[(size_t)(b0 + r) * DIM + c];
            *(float4*)&xs[r][512 + c] = *(const float4*)&x2[(size_t)(b0 + r) * DIM + c];
        }
        __syncthreads();
        const int lane = t & 63, w = t >> 6;        // wave w: rows 2w, 2w+1
        #pragma unroll
        for (int rr = 0; rr < 2; ++rr) {
            const int r = w * 2 + rr;
            float4 xv[4];
            #pragma unroll
            for (int i = 0; i < 4; ++i)
                xv[i] = *(const float4*)&xs[r][i * 256 + lane * 4];
            #pragma unroll
            for (int k0 = 0; k0 < KF; k0 += 4) {
                float s[4] = {0.f, 0.f, 0.f, 0.f};
                #pragma unroll
                for (int kk = 0; kk < 4; ++kk) {
                    const float* vrow = V + (size_t)(k0 + kk) * 1024;
                    #pragma unroll
                    for (int i = 0; i < 4; ++i) {
                        float4 vv = *(const float4*)&vrow[i * 256 + lane * 4];
                        s[kk] += vv.x * xv[i].x + vv.y * xv[i].y + vv.z * xv[i].z + vv.w * xv[i].w;
                    }
                }
                #pragma unroll
                for (int kk = 0; kk < 4; ++kk) {
                    float v = s[kk];
                    #pragma unroll
                    for (int off = 32; off; off >>= 1) v += __shfl_down(v, off);
                    if (lane == 0) vout[(size_t)(b0 + r) * KF + k0 + kk] = v;
                }
            }
        }
    } else if (bx < 1280) {
        // ---- cvt_x1: f32 -> bf16, 1024 blocks ----
        int i = (bx - 256) * 256 + t;               // 262144 float4 slots
        float4 v = *((const float4*)x1 + i);
        ushort4 r;
        r.x = f2bf(v.x); r.y = f2bf(v.y); r.z = f2bf(v.z); r.w = f2bf(v.w);
        *((ushort4*)x1b + i) = r;
    } else {
        // ---- cvt_wt: W f32 [512][16384] -> Wt bf16 [16384][512] ----
        ushort (*lt)[65] = (ushort(*)[65])sbuf;     // [64][65], +1 pad
        const int bxl = bx - 1280;                  // 0..2047
        const int n0 = (bxl >> 3) * 64;             // 256 values
        const int d0 = (bxl & 7) * 64;              // 8 values
        #pragma unroll
        for (int it = 0; it < 4; ++it) {
            int q = it * 256 + t;
            int dl = q >> 4;
            int n4 = (q & 15) * 4;
            float4 v = *(const float4*)&W[(size_t)(d0 + dl) * NCOL + n0 + n4];
            lt[n4 + 0][dl] = f2bf(v.x);
            lt[n4 + 1][dl] = f2bf(v.y);
            lt[n4 + 2][dl] = f2bf(v.z);
            lt[n4 + 3][dl] = f2bf(v.w);
        }
        __syncthreads();
        #pragma unroll
        for (int it = 0; it < 4; ++it) {
            int q = it * 256 + t;
            int nl = q >> 4;
            int d4 = (q & 15) * 4;
            ushort4 o;
            o.x = lt[nl][d4 + 0]; o.y = lt[nl][d4 + 1];
            o.z = lt[nl][d4 + 2]; o.w = lt[nl][d4 + 3];
            *(ushort4*)&Wt[(size_t)(n0 + nl) * DIM + d0 + d4] = o;
        }
    }
}

// ---- fused GEMM: block = (row tile i, j-group) covering 4 j-tiles ----
// Per j: K-loop (global_load_lds staging, XOR-swizzled source + reads),
// MFMA into acc, then e-contraction accumulated into persistent h_accum.
// h_accum written once: hpart[b][jg][k], 8MB.
__global__ void gemm_fused_kernel(const ushort* __restrict__ Ab,
                                  const ushort* __restrict__ Bt,
                                  const float* __restrict__ x2,
                                  float* __restrict__ hpart) {
    __shared__ __align__(16) char smem[32768];
    ushort* As = (ushort*)smem;               // [128][32] bf16, 8KB (linear dest)
    ushort* Bs = (ushort*)(smem + 8192);      // [128][32] bf16, 8KB (linear dest)
    float*  ha = (float*)(smem + 16384);      // h_accum [128][32] f32, 16KB

    const int jg = blockIdx.x;                // j-group 0..31
    const int i = blockIdx.y;                 // row tile 0..15
    const int t = threadIdx.x;
    const int lane = t & 63, wid = t >> 6;
    const int wr = wid >> 1, wc = wid & 1;    // wave grid 2x2, each 64x64
    const int row0 = i * 128;
    const int l15 = lane & 15, lk = (lane >> 4) * 8, lh = lane >> 4;

    const int sr = t >> 2;                                // 0..63
    const int scsw = ((t & 3) ^ ((sr & 6) >> 1)) * 8;     // swizzled ushort col
    const int lksw = lk ^ ((l15 & 6) << 2);               // matching read XOR

    // zero h_accum
    #pragma unroll
    for (int it = 0; it < 4; ++it) {
        float4 z = {0.f, 0.f, 0.f, 0.f};
        *(float4*)&ha[(it * 256 + t) * 4] = z;
    }
    __syncthreads();

    for (int jj = 0; jj < 4; ++jj) {
        const int j = jg * 4 + jj;
        const int col0 = j * 128;

        f32x4 acc[4][4] = {};

        for (int kt = 0; kt < DIM; kt += 32) {
            __builtin_amdgcn_global_load_lds(
                (gas_u32*)&Ab[(size_t)(row0 + sr) * DIM + kt + scsw],
                (las_u32*)&As[t * 8], 16, 0, 0);
            __builtin_amdgcn_global_load_lds(
                (gas_u32*)&Ab[(size_t)(row0 + 64 + sr) * DIM + kt + scsw],
                (las_u32*)&As[2048 + t * 8], 16, 0, 0);
            __builtin_amdgcn_global_load_lds(
                (gas_u32*)&Bt[(size_t)(col0 + sr) * DIM + kt + scsw],
                (las_u32*)&Bs[t * 8], 16, 0, 0);
            __builtin_amdgcn_global_load_lds(
                (gas_u32*)&Bt[(size_t)(col0 + 64 + sr) * DIM + kt + scsw],
                (las_u32*)&Bs[2048 + t * 8], 16, 0, 0);
            __syncthreads();
            bf16x8 af[4], bfr[4];
            #pragma unroll
            for (int m = 0; m < 4; ++m)
                af[m] = *(bf16x8*)&As[(wr * 64 + m * 16 + l15) * 32 + lksw];
            #pragma unroll
            for (int n = 0; n < 4; ++n)
                bfr[n] = *(bf16x8*)&Bs[(wc * 64 + n * 16 + l15) * 32 + lksw];
            #pragma unroll
            for (int m = 0; m < 4; ++m)
                #pragma unroll
                for (int n = 0; n < 4; ++n)
                    acc[m][n] = __builtin_amdgcn_mfma_f32_16x16x32_bf16(af[m], bfr[n], acc[m][n], 0, 0, 0);
            __syncthreads();
        }

        // e-contraction for this j, accumulated into h_accum.
        // acc[m][n][reg] = T[row0+wr*64+m*16+lh*4+reg][col0+wc*64+n*16+l15]
        const int e0 = j * 4 + wc * 2;        // this wave covers e0, e0+1
        if (wc == 0) {
            #pragma unroll
            for (int m = 0; m < 4; ++m) {
                #pragma unroll
                for (int reg = 0; reg < 4; ++reg) {
                    int row = wr * 64 + m * 16 + lh * 4 + reg;
                    float xa = x2[(size_t)(row0 + row) * DIM + e0];
                    float xb = x2[(size_t)(row0 + row) * DIM + e0 + 1];
                    ha[row * 32 + l15]      += acc[m][0][reg] * xa + acc[m][2][reg] * xb;
                    ha[row * 32 + 16 + l15] += acc[m][1][reg] * xa + acc[m][3][reg] * xb;
                }
            }
        }
        __syncthreads();
        if (wc == 1) {
            #pragma unroll
            for (int m = 0; m < 4; ++m) {
                #pragma unroll
                for (int reg = 0; reg < 4; ++reg) {
                    int row = wr * 64 + m * 16 + lh * 4 + reg;
                    float xa = x2[(size_t)(row0 + row) * DIM + e0];
                    float xb = x2[(size_t)(row0 + row) * DIM + e0 + 1];
                    ha[row * 32 + l15]      += acc[m][0][reg] * xa + acc[m][2][reg] * xb;
                    ha[row * 32 + 16 + l15] += acc[m][1][reg] * xa + acc[m][3][reg] * xb;
                }
            }
        }
        __syncthreads();
    }

    // write h_accum -> hpart[b = row0+row][jg][k]
    #pragma unroll
    for (int q = 0; q < 4; ++q) {
        int idx = q * 1024 + t * 4;           // float index in [128][32]
        int row = idx >> 5, kf = idx & 31;
        *(float4*)&hpart[(size_t)(row0 + row) * (JG * KF) + jg * KF + kf] =
            *(float4*)&ha[idx];
    }
}

// ---- final: wave-per-b. Sum hpart[b][0..31][k] over jg via shfl_xor,
//      add vout + bias, relu, dot U, store. No LDS, no serial stage. ----
__global__ void reduce_out_kernel(const float* __restrict__ hpart,
                                  const float* __restrict__ vout,
                                  const float* __restrict__ U,
                                  const float* __restrict__ bias,
                                  float* __restrict__ out) {
    const int t = threadIdx.x;
    const int lane = t & 63, w = t >> 6;
    const int b = blockIdx.x * 4 + w;         // 512 blocks x 4 waves

    const float* hb = hpart + (size_t)b * (JG * KF);
    const int jr = lane >> 3;                 // 0..7
    const int kq = lane & 7;                  // k-quad 0..7
    float4 a4 = {0.f, 0.f, 0.f, 0.f};
    #pragma unroll
    for (int p = 0; p < 4; ++p) {             // jg = p*8 + jr
        float4 v = *(const float4*)&hb[(p * 8 + jr) * KF + kq * 4];
        a4.x += v.x; a4.y += v.y; a4.z += v.z; a4.w += v.w;
    }
    // reduce over jr (lanes differing in bits 3..5)
    #pragma unroll
    for (int mask = 8; mask <= 32; mask <<= 1) {
        a4.x += __shfl_xor(a4.x, mask);
        a4.y += __shfl_xor(a4.y, mask);
        a4.z += __shfl_xor(a4.z, mask);
        a4.w += __shfl_xor(a4.w, mask);
    }
    // per-quad epilogue: relu(h + vout + bias) * U, summed over the quad
    float4 vo4 = *(const float4*)&vout[(size_t)b * KF + kq * 4];
    float4 bi4 = *(const float4*)&bias[kq * 4];
    float4 u4  = *(const float4*)&U[kq * 4];
    float p0 = fmaxf(a4.x + vo4.x + bi4.x, 0.f) * u4.x;
    float p1 = fmaxf(a4.y + vo4.y + bi4.y, 0.f) * u4.y;
    float p2 = fmaxf(a4.z + vo4.z + bi4.z, 0.f) * u4.z;
    float p3 = fmaxf(a4.w + vo4.w + bi4.w, 0.f) * u4.w;
    float p = p0 + p1 + p2 + p3;
    // reduce over kq (lanes differing in bits 0..2)
    #pragma unroll
    for (int mask = 1; mask <= 4; mask <<= 1) p += __shfl_xor(p, mask);
    if (lane == 0) out[b] = p;
}

extern "C" void kernel_launch(void* const* d_in, const int* in_sizes, int n_in,
                              void* d_out, int out_size, void* d_ws, size_t ws_size,
                              hipStream_t stream) {
    const float* x1   = (const float*)d_in[0];   // [2048][512]
    const float* x2   = (const float*)d_in[1];   // [2048][512]
    const float* W    = (const float*)d_in[2];   // [512][512][32]
    const float* V    = (const float*)d_in[3];   // [32][1024]
    const float* U    = (const float*)d_in[4];   // [32][1]
    const float* bias = (const float*)d_in[5];   // [32]
    float* out = (float*)d_out;                  // [2048]

    char* ws = (char*)d_ws;
    ushort* x1b = (ushort*)ws;                                   // 2 MB
    ushort* Wt  = (ushort*)(ws + (size_t)2 * 1024 * 1024);       // 16.8 MB
    float*  hp  = (float*)(ws + (size_t)19 * 1024 * 1024);       // 8 MB
    float*  vo  = (float*)(ws + (size_t)27 * 1024 * 1024);       // 256 KB

    fused_prep_kernel<<<dim3(3328), dim3(256), 0, stream>>>(x1, x2, W, V, x1b, Wt, vo);
    gemm_fused_kernel<<<dim3(JG, 16), dim3(256), 0, stream>>>(x1b, Wt, x2, hp);
    reduce_out_kernel<<<dim3(BATCH / 4), dim3(256), 0, stream>>>(hp, vo, U, bias, out);
}

// Round 12
// 158.306 us; speedup vs baseline: 1.7713x; 1.7713x over previous
//
#include <hip/hip_runtime.h>
#include <hip/hip_bf16.h>

// Problem: B=2048 pairs, D=512, K=32 features.
// out[b] = relu(x1[b]^T W[:,:,k] x2[b] + V[k].concat(x1,x2) + b[k]) @ U
// GEMM: T = x1_bf16 [2048x512] @ Wt_bf16^T, fused e-contraction with f32 x2.
// R8 swizzle: BANK_CONFLICT 4.98M->786K, dur unchanged (hidden under barrier
//     drain, T2-gate). R10: 155.6us, gemm 50.7.
// R11 REGRESSION: jg=4 grouping -> 512 blocks = 2 blocks/CU; occupancy 33->22%,
//     MfmaUtil 27.6->7.8%, gemm 173us. LESSON: keep >=8 blocks/CU; epilogue
//     traffic (32MB ~= 5us) never justifies losing barrier-drain hiding.
// R12: revert gemm to R10-exact; keep wave-per-b shfl reduce (no LDS, no
//     serial stage, analytically <=8us). Disambiguates the ~50us residual:
//     total ~150 -> prep/OH is the hog; total ~115-125 -> old reduce was.
// Workspace: x1b (2MB) | Wt (16MB) | hpart (32MB) | vout (256KB).

#define BATCH 2048
#define DIM 512
#define KF 32
#define NCOL (DIM * KF)      // 16384
#define JT (NCOL / 128)      // 128 column tiles

typedef __attribute__((ext_vector_type(8))) short bf16x8;
typedef __attribute__((ext_vector_type(4))) float f32x4;
typedef __attribute__((address_space(1))) const unsigned int gas_u32;
typedef __attribute__((address_space(3))) unsigned int las_u32;

static __device__ __forceinline__ ushort f2bf(float x) {
    __hip_bfloat16 h = __float2bfloat16(x);
    union { __hip_bfloat16 h; ushort u; } cv; cv.h = h;
    return cv.u;
}

// ---- fused prep: vout [0,256) | cvt_x1 [256,1280) | cvt_wt [1280,3328) ----
__global__ void fused_prep_kernel(const float* __restrict__ x1,
                                  const float* __restrict__ x2,
                                  const float* __restrict__ W,
                                  const float* __restrict__ V,
                                  ushort* __restrict__ x1b,
                                  ushort* __restrict__ Wt,
                                  float* __restrict__ vout) {
    __shared__ __align__(16) char sbuf[32768];
    const int bx = blockIdx.x;
    const int t = threadIdx.x;

    if (bx < 256) {
        // ---- vout: vout[b][k] = concat(x1[b],x2[b]) . V[k], k-unrolled x4 ----
        float (*xs)[1024] = (float(*)[1024])sbuf;   // 8 rows x 1024
        const int b0 = bx * 8;
        #pragma unroll
        for (int it = 0; it < 4; ++it) {
            int q = it * 256 + t;
            int r = q >> 7;
            int c = (q & 127) * 4;
            *(float4*)&xs[r][c]       = *(const float4*)&x1[(size_t)(b0 + r) * DIM + c];
            *(float4*)&xs[r][512 + c] = *(const float4*)&x2[(size_t)(b0 + r) * DIM + c];
        }
        __syncthreads();
        const int lane = t & 63, w = t >> 6;        // wave w: rows 2w, 2w+1
        #pragma unroll
        for (int rr = 0; rr < 2; ++rr) {
            const int r = w * 2 + rr;
            float4 xv[4];
            #pragma unroll
            for (int i = 0; i < 4; ++i)
                xv[i] = *(const float4*)&xs[r][i * 256 + lane * 4];
            #pragma unroll
            for (int k0 = 0; k0 < KF; k0 += 4) {
                float s[4] = {0.f, 0.f, 0.f, 0.f};
                #pragma unroll
                for (int kk = 0; kk < 4; ++kk) {
                    const float* vrow = V + (size_t)(k0 + kk) * 1024;
                    #pragma unroll
                    for (int i = 0; i < 4; ++i) {
                        float4 vv = *(const float4*)&vrow[i * 256 + lane * 4];
                        s[kk] += vv.x * xv[i].x + vv.y * xv[i].y + vv.z * xv[i].z + vv.w * xv[i].w;
                    }
                }
                #pragma unroll
                for (int kk = 0; kk < 4; ++kk) {
                    float v = s[kk];
                    #pragma unroll
                    for (int off = 32; off; off >>= 1) v += __shfl_down(v, off);
                    if (lane == 0) vout[(size_t)(b0 + r) * KF + k0 + kk] = v;
                }
            }
        }
    } else if (bx < 1280) {
        // ---- cvt_x1: f32 -> bf16, 1024 blocks ----
        int i = (bx - 256) * 256 + t;               // 262144 float4 slots
        float4 v = *((const float4*)x1 + i);
        ushort4 r;
        r.x = f2bf(v.x); r.y = f2bf(v.y); r.z = f2bf(v.z); r.w = f2bf(v.w);
        *((ushort4*)x1b + i) = r;
    } else {
        // ---- cvt_wt: W f32 [512][16384] -> Wt bf16 [16384][512] ----
        ushort (*lt)[65] = (ushort(*)[65])sbuf;     // [64][65], +1 pad
        const int bxl = bx - 1280;                  // 0..2047
        const int n0 = (bxl >> 3) * 64;             // 256 values
        const int d0 = (bxl & 7) * 64;              // 8 values
        #pragma unroll
        for (int it = 0; it < 4; ++it) {
            int q = it * 256 + t;
            int dl = q >> 4;
            int n4 = (q & 15) * 4;
            float4 v = *(const float4*)&W[(size_t)(d0 + dl) * NCOL + n0 + n4];
            lt[n4 + 0][dl] = f2bf(v.x);
            lt[n4 + 1][dl] = f2bf(v.y);
            lt[n4 + 2][dl] = f2bf(v.z);
            lt[n4 + 3][dl] = f2bf(v.w);
        }
        __syncthreads();
        #pragma unroll
        for (int it = 0; it < 4; ++it) {
            int q = it * 256 + t;
            int nl = q >> 4;
            int d4 = (q & 15) * 4;
            ushort4 o;
            o.x = lt[nl][d4 + 0]; o.y = lt[nl][d4 + 1];
            o.z = lt[nl][d4 + 2]; o.w = lt[nl][d4 + 3];
            *(ushort4*)&Wt[(size_t)(n0 + nl) * DIM + d0 + d4] = o;
        }
    }
}

// ---- fused GEMM (R10-exact): T-tile (128x128) + e-contraction -> hpart ----
// A = x1b [2048][512] bf16, Bt = Wt [16384][512] bf16 (i.e. W^T, rows = n)
// h_part[b][j][k] = sum_{e in tile j} T[b, e*32+k] * x2[b][e]
// LDS tiles XOR-swizzled: stored chunk (r,c) holds logical (r, c^((r&6)>>1)),
// via permuted GLOBAL source (LDS dest linear for global_load_lds) + same
// XOR on fragment reads (row&6 == l15&6 for all m, so XORs cancel exactly).
__global__ void gemm_fused_kernel(const ushort* __restrict__ Ab,
                                  const ushort* __restrict__ Bt,
                                  const float* __restrict__ x2,
                                  float* __restrict__ hpart) {
    __shared__ __align__(16) char smem[16384];
    ushort* As = (ushort*)smem;               // [128][32] bf16, 8KB (linear dest)
    ushort* Bs = (ushort*)(smem + 8192);      // [128][32] bf16, 8KB (linear dest)
    float*  hp = (float*)smem;                // [128][32] f32 epilogue reuse, 16KB

    const int j = blockIdx.x;                 // column tile 0..127
    const int i = blockIdx.y;                 // row tile 0..15
    const int t = threadIdx.x;
    const int lane = t & 63, wid = t >> 6;
    const int wr = wid >> 1, wc = wid & 1;    // wave grid 2x2, each 64x64
    const int row0 = i * 128, col0 = j * 128;
    const int l15 = lane & 15, lk = (lane >> 4) * 8, lh = lane >> 4;

    const int sr = t >> 2;                                // 0..63
    const int scsw = ((t & 3) ^ ((sr & 6) >> 1)) * 8;     // swizzled ushort col
    const int lksw = lk ^ ((l15 & 6) << 2);               // matching read XOR

    f32x4 acc[4][4] = {};

    for (int kt = 0; kt < DIM; kt += 32) {
        __builtin_amdgcn_global_load_lds(
            (gas_u32*)&Ab[(size_t)(row0 + sr) * DIM + kt + scsw],
            (las_u32*)&As[t * 8], 16, 0, 0);
        __builtin_amdgcn_global_load_lds(
            (gas_u32*)&Ab[(size_t)(row0 + 64 + sr) * DIM + kt + scsw],
            (las_u32*)&As[2048 + t * 8], 16, 0, 0);
        __builtin_amdgcn_global_load_lds(
            (gas_u32*)&Bt[(size_t)(col0 + sr) * DIM + kt + scsw],
            (las_u32*)&Bs[t * 8], 16, 0, 0);
        __builtin_amdgcn_global_load_lds(
            (gas_u32*)&Bt[(size_t)(col0 + 64 + sr) * DIM + kt + scsw],
            (las_u32*)&Bs[2048 + t * 8], 16, 0, 0);
        __syncthreads();
        bf16x8 af[4], bfr[4];
        #pragma unroll
        for (int m = 0; m < 4; ++m)
            af[m] = *(bf16x8*)&As[(wr * 64 + m * 16 + l15) * 32 + lksw];
        #pragma unroll
        for (int n = 0; n < 4; ++n)
            bfr[n] = *(bf16x8*)&Bs[(wc * 64 + n * 16 + l15) * 32 + lksw];
        #pragma unroll
        for (int m = 0; m < 4; ++m)
            #pragma unroll
            for (int n = 0; n < 4; ++n)
                acc[m][n] = __builtin_amdgcn_mfma_f32_16x16x32_bf16(af[m], bfr[n], acc[m][n], 0, 0, 0);
        __syncthreads();
    }

    // Epilogue: contract the 4 e-values of this tile with x2 (f32).
    // acc[m][n][reg] = T[row0+wr*64+m*16+lh*4+reg][col0+wc*64+n*16+l15]
    const int e0 = j * 4 + wc * 2;            // this wave covers e0, e0+1
    if (wc == 0) {
        #pragma unroll
        for (int m = 0; m < 4; ++m) {
            #pragma unroll
            for (int reg = 0; reg < 4; ++reg) {
                int row = wr * 64 + m * 16 + lh * 4 + reg;
                float xa = x2[(size_t)(row0 + row) * DIM + e0];
                float xb = x2[(size_t)(row0 + row) * DIM + e0 + 1];
                hp[row * 32 + l15]      = acc[m][0][reg] * xa + acc[m][2][reg] * xb;
                hp[row * 32 + 16 + l15] = acc[m][1][reg] * xa + acc[m][3][reg] * xb;
            }
        }
    }
    __syncthreads();
    if (wc == 1) {
        #pragma unroll
        for (int m = 0; m < 4; ++m) {
            #pragma unroll
            for (int reg = 0; reg < 4; ++reg) {
                int row = wr * 64 + m * 16 + lh * 4 + reg;
                float xa = x2[(size_t)(row0 + row) * DIM + e0];
                float xb = x2[(size_t)(row0 + row) * DIM + e0 + 1];
                hp[row * 32 + l15]      += acc[m][0][reg] * xa + acc[m][2][reg] * xb;
                hp[row * 32 + 16 + l15] += acc[m][1][reg] * xa + acc[m][3][reg] * xb;
            }
        }
    }
    __syncthreads();
    // write h_part[b = row0+row][j][kfeat]
    #pragma unroll
    for (int q = 0; q < 4; ++q) {
        int idx = q * 1024 + t * 4;
        int row = idx >> 5, kf = idx & 31;
        *(float4*)&hpart[(size_t)(row0 + row) * (JT * KF) + j * KF + kf] = *(float4*)&hp[idx];
    }
}

// ---- final: wave-per-b. Sum hpart[b][0..127][k] over j via shfl_xor,
//      add vout + bias, relu, dot U, store. No LDS, no serial stage. ----
__global__ void reduce_out_kernel(const float* __restrict__ hpart,
                                  const float* __restrict__ vout,
                                  const float* __restrict__ U,
                                  const float* __restrict__ bias,
                                  float* __restrict__ out) {
    const int t = threadIdx.x;
    const int lane = t & 63, w = t >> 6;
    const int b = blockIdx.x * 4 + w;         // 512 blocks x 4 waves

    const float* hb = hpart + (size_t)b * (JT * KF);
    const int jr = lane >> 3;                 // 0..7
    const int kq = lane & 7;                  // k-quad 0..7
    float4 a4 = {0.f, 0.f, 0.f, 0.f};
    #pragma unroll
    for (int p = 0; p < 16; ++p) {            // j = p*8 + jr
        float4 v = *(const float4*)&hb[(p * 8 + jr) * KF + kq * 4];
        a4.x += v.x; a4.y += v.y; a4.z += v.z; a4.w += v.w;
    }
    // reduce over jr (lanes differing in bits 3..5)
    #pragma unroll
    for (int mask = 8; mask <= 32; mask <<= 1) {
        a4.x += __shfl_xor(a4.x, mask);
        a4.y += __shfl_xor(a4.y, mask);
        a4.z += __shfl_xor(a4.z, mask);
        a4.w += __shfl_xor(a4.w, mask);
    }
    // per-quad epilogue: relu(h + vout + bias) * U, summed over the quad
    float4 vo4 = *(const float4*)&vout[(size_t)b * KF + kq * 4];
    float4 bi4 = *(const float4*)&bias[kq * 4];
    float4 u4  = *(const float4*)&U[kq * 4];
    float p0 = fmaxf(a4.x + vo4.x + bi4.x, 0.f) * u4.x;
    float p1 = fmaxf(a4.y + vo4.y + bi4.y, 0.f) * u4.y;
    float p2 = fmaxf(a4.z + vo4.z + bi4.z, 0.f) * u4.z;
    float p3 = fmaxf(a4.w + vo4.w + bi4.w, 0.f) * u4.w;
    float p = p0 + p1 + p2 + p3;
    // reduce over kq (lanes differing in bits 0..2)
    #pragma unroll
    for (int mask = 1; mask <= 4; mask <<= 1) p += __shfl_xor(p, mask);
    if (lane == 0) out[b] = p;
}

extern "C" void kernel_launch(void* const* d_in, const int* in_sizes, int n_in,
                              void* d_out, int out_size, void* d_ws, size_t ws_size,
                              hipStream_t stream) {
    const float* x1   = (const float*)d_in[0];   // [2048][512]
    const float* x2   = (const float*)d_in[1];   // [2048][512]
    const float* W    = (const float*)d_in[2];   // [512][512][32]
    const float* V    = (const float*)d_in[3];   // [32][1024]
    const float* U    = (const float*)d_in[4];   // [32][1]
    const float* bias = (const float*)d_in[5];   // [32]
    float* out = (float*)d_out;                  // [2048]

    char* ws = (char*)d_ws;
    ushort* x1b = (ushort*)ws;                                   // 2 MB
    ushort* Wt  = (ushort*)(ws + (size_t)2 * 1024 * 1024);       // 16 MB
    float*  hp  = (float*)(ws + (size_t)18 * 1024 * 1024);       // 32 MB
    float*  vo  = (float*)(ws + (size_t)50 * 1024 * 1024);       // 256 KB

    fused_prep_kernel<<<dim3(3328), dim3(256), 0, stream>>>(x1, x2, W, V, x1b, Wt, vo);
    gemm_fused_kernel<<<dim3(JT, 16), dim3(256), 0, stream>>>(x1b, Wt, x2, hp);
    reduce_out_kernel<<<dim3(BATCH / 4), dim3(256), 0, stream>>>(hp, vo, U, bias, out);
}

// Round 13
// 154.449 us; speedup vs baseline: 1.8156x; 1.0250x over previous
//
#include <hip/hip_runtime.h>
#include <hip/hip_bf16.h>

// Problem: B=2048 pairs, D=512, K=32 features.
// out[b] = relu(x1[b]^T W[:,:,k] x2[b] + V[k].concat(x1,x2) + b[k]) @ U
// GEMM: T = x1_bf16 [2048x512] @ Wt_bf16^T, fused e-contraction with f32 x2.
// R10: 155.6us, gemm 50.7. R11 REGRESSION (jg-group, 2 blk/CU): reverted.
// R12: new wave-per-b reduce changed NOTHING (158.3) -> old reduce was never
//     the hog. Accounting: gemm 54 + reduce ~8 + [prep + fixed-OH ~= 95us,
//     split UNKNOWN] -- top-5 is all gemm replicates (54 > everything).
// R13 DIAGNOSTIC: split gemm into 2 half-dispatches (~27us each) so any
//     prep dispatch >28us MUST surface in top-5 with counters. + vout TLP
//     (512 blocks x 4 rows). All math identical.
// Workspace: x1b (2MB) | Wt (16MB) | hpart (32MB) | vout (256KB).

#define BATCH 2048
#define DIM 512
#define KF 32
#define NCOL (DIM * KF)      // 16384
#define JT (NCOL / 128)      // 128 column tiles

typedef __attribute__((ext_vector_type(8))) short bf16x8;
typedef __attribute__((ext_vector_type(4))) float f32x4;
typedef __attribute__((address_space(1))) const unsigned int gas_u32;
typedef __attribute__((address_space(3))) unsigned int las_u32;

static __device__ __forceinline__ ushort f2bf(float x) {
    __hip_bfloat16 h = __float2bfloat16(x);
    union { __hip_bfloat16 h; ushort u; } cv; cv.h = h;
    return cv.u;
}

// ---- fused prep: vout [0,512) | cvt_x1 [512,1536) | cvt_wt [1536,3584) ----
__global__ void fused_prep_kernel(const float* __restrict__ x1,
                                  const float* __restrict__ x2,
                                  const float* __restrict__ W,
                                  const float* __restrict__ V,
                                  ushort* __restrict__ x1b,
                                  ushort* __restrict__ Wt,
                                  float* __restrict__ vout) {
    __shared__ __align__(16) char sbuf[16384];
    const int bx = blockIdx.x;
    const int t = threadIdx.x;

    if (bx < 512) {
        // ---- vout: vout[b][k] = concat(x1[b],x2[b]) . V[k], 4 rows/block ----
        float (*xs)[1024] = (float(*)[1024])sbuf;   // 4 rows x 1024, 16KB
        const int b0 = bx * 4;
        #pragma unroll
        for (int it = 0; it < 4; ++it) {
            int q = it * 256 + t;                   // 0..1023 float4 slots
            int r = q >> 8;                         // 0..3
            int s = q & 255;
            if (s < 128) {
                *(float4*)&xs[r][s * 4] = *(const float4*)&x1[(size_t)(b0 + r) * DIM + s * 4];
            } else {
                *(float4*)&xs[r][512 + (s - 128) * 4] =
                    *(const float4*)&x2[(size_t)(b0 + r) * DIM + (s - 128) * 4];
            }
        }
        __syncthreads();
        const int lane = t & 63, w = t >> 6;        // wave w handles row w
        const int r = w;
        float4 xv[4];
        #pragma unroll
        for (int i = 0; i < 4; ++i)
            xv[i] = *(const float4*)&xs[r][i * 256 + lane * 4];
        #pragma unroll
        for (int k0 = 0; k0 < KF; k0 += 4) {
            float s[4] = {0.f, 0.f, 0.f, 0.f};
            #pragma unroll
            for (int kk = 0; kk < 4; ++kk) {
                const float* vrow = V + (size_t)(k0 + kk) * 1024;
                #pragma unroll
                for (int i = 0; i < 4; ++i) {
                    float4 vv = *(const float4*)&vrow[i * 256 + lane * 4];
                    s[kk] += vv.x * xv[i].x + vv.y * xv[i].y + vv.z * xv[i].z + vv.w * xv[i].w;
                }
            }
            #pragma unroll
            for (int kk = 0; kk < 4; ++kk) {
                float v = s[kk];
                #pragma unroll
                for (int off = 32; off; off >>= 1) v += __shfl_down(v, off);
                if (lane == 0) vout[(size_t)(b0 + r) * KF + k0 + kk] = v;
            }
        }
    } else if (bx < 1536) {
        // ---- cvt_x1: f32 -> bf16, 1024 blocks ----
        int i = (bx - 512) * 256 + t;               // 262144 float4 slots
        float4 v = *((const float4*)x1 + i);
        ushort4 r;
        r.x = f2bf(v.x); r.y = f2bf(v.y); r.z = f2bf(v.z); r.w = f2bf(v.w);
        *((ushort4*)x1b + i) = r;
    } else {
        // ---- cvt_wt: W f32 [512][16384] -> Wt bf16 [16384][512] ----
        ushort (*lt)[65] = (ushort(*)[65])sbuf;     // [64][65], +1 pad
        const int bxl = bx - 1536;                  // 0..2047
        const int n0 = (bxl >> 3) * 64;             // 256 values
        const int d0 = (bxl & 7) * 64;              // 8 values
        #pragma unroll
        for (int it = 0; it < 4; ++it) {
            int q = it * 256 + t;
            int dl = q >> 4;
            int n4 = (q & 15) * 4;
            float4 v = *(const float4*)&W[(size_t)(d0 + dl) * NCOL + n0 + n4];
            lt[n4 + 0][dl] = f2bf(v.x);
            lt[n4 + 1][dl] = f2bf(v.y);
            lt[n4 + 2][dl] = f2bf(v.z);
            lt[n4 + 3][dl] = f2bf(v.w);
        }
        __syncthreads();
        #pragma unroll
        for (int it = 0; it < 4; ++it) {
            int q = it * 256 + t;
            int nl = q >> 4;
            int d4 = (q & 15) * 4;
            ushort4 o;
            o.x = lt[nl][d4 + 0]; o.y = lt[nl][d4 + 1];
            o.z = lt[nl][d4 + 2]; o.w = lt[nl][d4 + 3];
            *(ushort4*)&Wt[(size_t)(n0 + nl) * DIM + d0 + d4] = o;
        }
    }
}

// ---- fused GEMM (R10-exact math, i0 row offset for split dispatch) ----
// h_part[b][j][k] = sum_{e in tile j} T[b, e*32+k] * x2[b][e]
__global__ void gemm_fused_kernel(const ushort* __restrict__ Ab,
                                  const ushort* __restrict__ Bt,
                                  const float* __restrict__ x2,
                                  float* __restrict__ hpart,
                                  int i0) {
    __shared__ __align__(16) char smem[16384];
    ushort* As = (ushort*)smem;               // [128][32] bf16, 8KB (linear dest)
    ushort* Bs = (ushort*)(smem + 8192);      // [128][32] bf16, 8KB (linear dest)
    float*  hp = (float*)smem;                // [128][32] f32 epilogue reuse, 16KB

    const int j = blockIdx.x;                 // column tile 0..127
    const int i = blockIdx.y + i0;            // row tile (split dispatch)
    const int t = threadIdx.x;
    const int lane = t & 63, wid = t >> 6;
    const int wr = wid >> 1, wc = wid & 1;    // wave grid 2x2, each 64x64
    const int row0 = i * 128, col0 = j * 128;
    const int l15 = lane & 15, lk = (lane >> 4) * 8, lh = lane >> 4;

    const int sr = t >> 2;                                // 0..63
    const int scsw = ((t & 3) ^ ((sr & 6) >> 1)) * 8;     // swizzled ushort col
    const int lksw = lk ^ ((l15 & 6) << 2);               // matching read XOR

    f32x4 acc[4][4] = {};

    for (int kt = 0; kt < DIM; kt += 32) {
        __builtin_amdgcn_global_load_lds(
            (gas_u32*)&Ab[(size_t)(row0 + sr) * DIM + kt + scsw],
            (las_u32*)&As[t * 8], 16, 0, 0);
        __builtin_amdgcn_global_load_lds(
            (gas_u32*)&Ab[(size_t)(row0 + 64 + sr) * DIM + kt + scsw],
            (las_u32*)&As[2048 + t * 8], 16, 0, 0);
        __builtin_amdgcn_global_load_lds(
            (gas_u32*)&Bt[(size_t)(col0 + sr) * DIM + kt + scsw],
            (las_u32*)&Bs[t * 8], 16, 0, 0);
        __builtin_amdgcn_global_load_lds(
            (gas_u32*)&Bt[(size_t)(col0 + 64 + sr) * DIM + kt + scsw],
            (las_u32*)&Bs[2048 + t * 8], 16, 0, 0);
        __syncthreads();
        bf16x8 af[4], bfr[4];
        #pragma unroll
        for (int m = 0; m < 4; ++m)
            af[m] = *(bf16x8*)&As[(wr * 64 + m * 16 + l15) * 32 + lksw];
        #pragma unroll
        for (int n = 0; n < 4; ++n)
            bfr[n] = *(bf16x8*)&Bs[(wc * 64 + n * 16 + l15) * 32 + lksw];
        #pragma unroll
        for (int m = 0; m < 4; ++m)
            #pragma unroll
            for (int n = 0; n < 4; ++n)
                acc[m][n] = __builtin_amdgcn_mfma_f32_16x16x32_bf16(af[m], bfr[n], acc[m][n], 0, 0, 0);
        __syncthreads();
    }

    // Epilogue: contract the 4 e-values of this tile with x2 (f32).
    const int e0 = j * 4 + wc * 2;            // this wave covers e0, e0+1
    if (wc == 0) {
        #pragma unroll
        for (int m = 0; m < 4; ++m) {
            #pragma unroll
            for (int reg = 0; reg < 4; ++reg) {
                int row = wr * 64 + m * 16 + lh * 4 + reg;
                float xa = x2[(size_t)(row0 + row) * DIM + e0];
                float xb = x2[(size_t)(row0 + row) * DIM + e0 + 1];
                hp[row * 32 + l15]      = acc[m][0][reg] * xa + acc[m][2][reg] * xb;
                hp[row * 32 + 16 + l15] = acc[m][1][reg] * xa + acc[m][3][reg] * xb;
            }
        }
    }
    __syncthreads();
    if (wc == 1) {
        #pragma unroll
        for (int m = 0; m < 4; ++m) {
            #pragma unroll
            for (int reg = 0; reg < 4; ++reg) {
                int row = wr * 64 + m * 16 + lh * 4 + reg;
                float xa = x2[(size_t)(row0 + row) * DIM + e0];
                float xb = x2[(size_t)(row0 + row) * DIM + e0 + 1];
                hp[row * 32 + l15]      += acc[m][0][reg] * xa + acc[m][2][reg] * xb;
                hp[row * 32 + 16 + l15] += acc[m][1][reg] * xa + acc[m][3][reg] * xb;
            }
        }
    }
    __syncthreads();
    // write h_part[b = row0+row][j][kfeat]
    #pragma unroll
    for (int q = 0; q < 4; ++q) {
        int idx = q * 1024 + t * 4;
        int row = idx >> 5, kf = idx & 31;
        *(float4*)&hpart[(size_t)(row0 + row) * (JT * KF) + j * KF + kf] = *(float4*)&hp[idx];
    }
}

// ---- final: wave-per-b. Sum hpart[b][0..127][k] over j via shfl_xor,
//      add vout + bias, relu, dot U, store. ----
__global__ void reduce_out_kernel(const float* __restrict__ hpart,
                                  const float* __restrict__ vout,
                                  const float* __restrict__ U,
                                  const float* __restrict__ bias,
                                  float* __restrict__ out) {
    const int t = threadIdx.x;
    const int lane = t & 63, w = t >> 6;
    const int b = blockIdx.x * 4 + w;         // 512 blocks x 4 waves

    const float* hb = hpart + (size_t)b * (JT * KF);
    const int jr = lane >> 3;                 // 0..7
    const int kq = lane & 7;                  // k-quad 0..7
    float4 a4 = {0.f, 0.f, 0.f, 0.f};
    #pragma unroll
    for (int p = 0; p < 16; ++p) {            // j = p*8 + jr
        float4 v = *(const float4*)&hb[(p * 8 + jr) * KF + kq * 4];
        a4.x += v.x; a4.y += v.y; a4.z += v.z; a4.w += v.w;
    }
    #pragma unroll
    for (int mask = 8; mask <= 32; mask <<= 1) {
        a4.x += __shfl_xor(a4.x, mask);
        a4.y += __shfl_xor(a4.y, mask);
        a4.z += __shfl_xor(a4.z, mask);
        a4.w += __shfl_xor(a4.w, mask);
    }
    float4 vo4 = *(const float4*)&vout[(size_t)b * KF + kq * 4];
    float4 bi4 = *(const float4*)&bias[kq * 4];
    float4 u4  = *(const float4*)&U[kq * 4];
    float p0 = fmaxf(a4.x + vo4.x + bi4.x, 0.f) * u4.x;
    float p1 = fmaxf(a4.y + vo4.y + bi4.y, 0.f) * u4.y;
    float p2 = fmaxf(a4.z + vo4.z + bi4.z, 0.f) * u4.z;
    float p3 = fmaxf(a4.w + vo4.w + bi4.w, 0.f) * u4.w;
    float p = p0 + p1 + p2 + p3;
    #pragma unroll
    for (int mask = 1; mask <= 4; mask <<= 1) p += __shfl_xor(p, mask);
    if (lane == 0) out[b] = p;
}

extern "C" void kernel_launch(void* const* d_in, const int* in_sizes, int n_in,
                              void* d_out, int out_size, void* d_ws, size_t ws_size,
                              hipStream_t stream) {
    const float* x1   = (const float*)d_in[0];   // [2048][512]
    const float* x2   = (const float*)d_in[1];   // [2048][512]
    const float* W    = (const float*)d_in[2];   // [512][512][32]
    const float* V    = (const float*)d_in[3];   // [32][1024]
    const float* U    = (const float*)d_in[4];   // [32][1]
    const float* bias = (const float*)d_in[5];   // [32]
    float* out = (float*)d_out;                  // [2048]

    char* ws = (char*)d_ws;
    ushort* x1b = (ushort*)ws;                                   // 2 MB
    ushort* Wt  = (ushort*)(ws + (size_t)2 * 1024 * 1024);       // 16 MB
    float*  hp  = (float*)(ws + (size_t)18 * 1024 * 1024);       // 32 MB
    float*  vo  = (float*)(ws + (size_t)50 * 1024 * 1024);       // 256 KB

    fused_prep_kernel<<<dim3(3584), dim3(256), 0, stream>>>(x1, x2, W, V, x1b, Wt, vo);
    gemm_fused_kernel<<<dim3(JT, 8), dim3(256), 0, stream>>>(x1b, Wt, x2, hp, 0);
    gemm_fused_kernel<<<dim3(JT, 8), dim3(256), 0, stream>>>(x1b, Wt, x2, hp, 8);
    reduce_out_kernel<<<dim3(BATCH / 4), dim3(256), 0, stream>>>(hp, vo, U, bias, out);
}